// Round 20
// baseline (239.139 us; speedup 1.0000x reference)
//
#include <hip/hip_runtime.h>
#include <hip/hip_bf16.h>

// Problem constants
#define BATCH 32
#define LQ 64
#define LD 512
#define EMB 300
#define FFH 100
#define ATTD 32
#define NH 8
#define NK 21
#define MQ (BATCH * LQ)          // 2048 query tokens
#define MD (BATCH * LD)          // 16384 doc tokens
#define MALL (MQ + MD)           // 18432 merged tokens

typedef __attribute__((ext_vector_type(8))) short bf16x8;
typedef __attribute__((ext_vector_type(4))) float f32x4;

__device__ __forceinline__ float wave_sum(float v) {
    #pragma unroll
    for (int off = 32; off > 0; off >>= 1) v += __shfl_xor(v, off);
    return v;
}

__device__ __forceinline__ float bf2f(__hip_bfloat16 h) { return __bfloat162float(h); }

// 4 consecutive bf16 -> float4 (8B-aligned source)
__device__ __forceinline__ float4 bf4_to_f4(const __hip_bfloat16* p) {
    uint2 u = *(const uint2*)p;
    float4 f;
    f.x = __uint_as_float((u.x & 0xffffu) << 16);
    f.y = __uint_as_float(u.x & 0xffff0000u);
    f.z = __uint_as_float((u.y & 0xffffu) << 16);
    f.w = __uint_as_float(u.y & 0xffff0000u);
    return f;
}

__device__ __forceinline__ unsigned short f2bfu(float x) {
    __hip_bfloat16 h = __float2bfloat16(x);
    return *(unsigned short*)&h;
}

// ---------------- fused prep: masked embeddings + masks + all weights + out zero ---------
__global__ void prep_all(const float* __restrict__ qe, const float* __restrict__ de,
                         const float* __restrict__ mq, const float* __restrict__ md,
                         const float* __restrict__ w1, const float* __restrict__ w2,
                         const float* __restrict__ aw, const float* __restrict__ ow,
                         __hip_bfloat16* __restrict__ xbf, float* __restrict__ mall,
                         __hip_bfloat16* __restrict__ w1t, __hip_bfloat16* __restrict__ w2t,
                         __hip_bfloat16* __restrict__ awt, __hip_bfloat16* __restrict__ owt,
                         float* __restrict__ out) {
    int i = blockIdx.x * blockDim.x + threadIdx.x;
    const int NQ4 = MALL * (EMB / 4);             // 1,382,400 float4 chunks
    if (i < NQ4) {
        int tok = i / (EMB / 4), c4 = (i % (EMB / 4)) * 4;
        float m;
        float4 v;
        if (tok < MQ) {
            m = mq[tok];
            v = *(const float4*)(qe + (size_t)tok * EMB + c4);
        } else {
            m = md[tok - MQ];
            v = *(const float4*)(de + (size_t)(tok - MQ) * EMB + c4);
        }
        uint2 u;
        u.x = (unsigned)f2bfu(v.x * m) | ((unsigned)f2bfu(v.y * m) << 16);
        u.y = (unsigned)f2bfu(v.z * m) | ((unsigned)f2bfu(v.w * m) << 16);
        *(uint2*)(xbf + (size_t)tok * EMB + c4) = u;
        if (c4 == 0) mall[tok] = m;
        return;
    }
    int j = i - NQ4;
    if (j < 2 * EMB * FFH) {                      // w1t: w1[l][k][n] -> [l][n][k]
        int l = j / (EMB * FFH), r = j % (EMB * FFH);
        int k = r / FFH, n = r % FFH;
        w1t[(size_t)l * FFH * EMB + (size_t)n * EMB + k] = __float2bfloat16(w1[j]);
        return;
    }
    j -= 2 * EMB * FFH;
    if (j < 2 * 320 * 128) {                      // w2t zero-padded [l][320][128]
        int l = j / (320 * 128), r = j % (320 * 128);
        int n = r / 128, k = r % 128;
        float v = (n < EMB && k < FFH) ? w2[(size_t)l * FFH * EMB + (size_t)k * EMB + n] : 0.f;
        w2t[j] = __float2bfloat16(v);
        return;
    }
    j -= 2 * 320 * 128;
    if (j < 2 * EMB * 96) {                       // awt: aw[l][k][n] -> [l][n][k]
        int l = j / (EMB * 96), r = j % (EMB * 96);
        int k = r / 96, n = r % 96;
        awt[(size_t)l * 96 * EMB + (size_t)n * EMB + k] = __float2bfloat16(aw[j]);
        return;
    }
    j -= 2 * EMB * 96;
    if (j < 2 * 320 * 32) {                       // owt zero-padded [l][320][32]
        int l = j / (320 * 32), r = j % (320 * 32);
        int n = r / 32, k = r % 32;
        float v = (n < EMB) ? ow[(size_t)l * ATTD * EMB + (size_t)k * EMB + n] : 0.f;
        owt[j] = __float2bfloat16(v);
        return;
    }
    j -= 2 * 320 * 32;
    if (j < BATCH) out[j] = 0.f;                  // zero output accumulators
}

// ---------------- shared staging helper: 8 bf16 of one row ----------------
__device__ __forceinline__ void stage_row8(const __hip_bfloat16* __restrict__ src, bool rowvalid,
                                           int K, int gk, __hip_bfloat16* dst) {
    if (rowvalid && gk + 8 <= K) {
        const uint2* p = (const uint2*)(src + gk);
        uint2 a = p[0], b = p[1];
        *(uint2*)dst = a;
        *(uint2*)(dst + 4) = b;
    } else {
        #pragma unroll
        for (int j = 0; j < 8; j++)
            dst[j] = (rowvalid && gk + j < K) ? src[gk + j] : __float2bfloat16(0.f);
    }
}

// ---------------- MFMA bf16 GEMM: Cb[M,Ns] = A[M,K] @ Bt[Nr,K]^T + bias (+relu) ---------
template <bool RELU>
__global__ __launch_bounds__(256) void gemm_mfma(const __hip_bfloat16* __restrict__ A,
                                                 const __hip_bfloat16* __restrict__ Bt,
                                                 const float* __restrict__ bias,
                                                 __hip_bfloat16* __restrict__ Cb,
                                                 int M, int Nr, int Ns, int K) {
    __shared__ __align__(16) __hip_bfloat16 As[64][40];
    __shared__ __align__(16) __hip_bfloat16 Bs[64][40];
    const int tid = threadIdx.x;
    const int m0 = blockIdx.y * 64, n0 = blockIdx.x * 64;
    const int lane = tid & 63;
    const int wv = tid >> 6;
    const int wm = wv >> 1, wn = wv & 1;
    const int l15 = lane & 15, lg = lane >> 4;
    const int srow = tid >> 2, sk8 = (tid & 3) * 8;
    f32x4 acc[2][2] = {};
    const int NS = (K + 31) >> 5;
    const __hip_bfloat16* arow = A + (size_t)(m0 + srow) * K;
    const bool bvalid = (n0 + srow) < Nr;
    const __hip_bfloat16* brow = Bt + (size_t)(n0 + srow) * K;

    for (int s = 0; s < NS; s++) {
        const int gk = (s << 5) + sk8;
        if (s) __syncthreads();
        stage_row8(arow, true, K, gk, &As[srow][sk8]);
        stage_row8(brow, bvalid, K, gk, &Bs[srow][sk8]);
        __syncthreads();
        bf16x8 af0 = *(const bf16x8*)&As[wm * 32 + l15][lg * 8];
        bf16x8 af1 = *(const bf16x8*)&As[wm * 32 + 16 + l15][lg * 8];
        bf16x8 bf0 = *(const bf16x8*)&Bs[wn * 32 + l15][lg * 8];
        bf16x8 bf1 = *(const bf16x8*)&Bs[wn * 32 + 16 + l15][lg * 8];
        acc[0][0] = __builtin_amdgcn_mfma_f32_16x16x32_bf16(af0, bf0, acc[0][0], 0, 0, 0);
        acc[0][1] = __builtin_amdgcn_mfma_f32_16x16x32_bf16(af0, bf1, acc[0][1], 0, 0, 0);
        acc[1][0] = __builtin_amdgcn_mfma_f32_16x16x32_bf16(af1, bf0, acc[1][0], 0, 0, 0);
        acc[1][1] = __builtin_amdgcn_mfma_f32_16x16x32_bf16(af1, bf1, acc[1][1], 0, 0, 0);
    }

    #pragma unroll
    for (int fc = 0; fc < 2; fc++) {
        int col = n0 + wn * 32 + fc * 16 + l15;
        if (col >= Ns) continue;
        float bs = (col < Nr) ? bias[col] : 0.f;
        #pragma unroll
        for (int fr = 0; fr < 2; fr++) {
            int rbase = m0 + wm * 32 + fr * 16 + lg * 4;
            #pragma unroll
            for (int r = 0; r < 4; r++) {
                float v = acc[fr][fc][r] + bs;
                if (RELU) v = fmaxf(v, 0.f);
                Cb[(size_t)(rbase + r) * Ns + col] = __float2bfloat16(v);
            }
        }
    }
}

// ---------------- DIRECT-OPERAND GEMM + residual + LayerNorm (N = 300, no LDS) ----------
// MIX: additionally fold mix+L2-normalize: out = normalize((mx*xorig + (1-mx)*LN)*mask).
template <int NSTEP, int KSTR, int ASTR, bool MIX>
__global__ __launch_bounds__(256) void gemm_ln_direct(const __hip_bfloat16* __restrict__ A,
                                                      const __hip_bfloat16* __restrict__ Bt,
                                                      const float* __restrict__ bias,
                                                      const __hip_bfloat16* __restrict__ Res,
                                                      const float* __restrict__ g,
                                                      const float* __restrict__ beta,
                                                      __hip_bfloat16* __restrict__ Y,
                                                      const __hip_bfloat16* __restrict__ Xorig,
                                                      const float* __restrict__ mall,
                                                      const float* __restrict__ mixer) {
    const int tid = threadIdx.x;
    const int wv = tid >> 6;
    const int lane = tid & 63;
    const int l15 = lane & 15, lg = lane >> 4;
    const int m0 = blockIdx.x * 64 + wv * 16;

    f32x4 acc[19];
    #pragma unroll
    for (int fc = 0; fc < 19; fc++) acc[fc] = (f32x4){0.f, 0.f, 0.f, 0.f};

    #pragma unroll
    for (int ks = 0; ks < NSTEP; ks++) {
        const int kb = ks * 32 + lg * 8;
        bf16x8 af = *(const bf16x8*)(A + (size_t)(m0 + l15) * ASTR + kb);
        #pragma unroll
        for (int fc = 0; fc < 19; fc++) {
            bf16x8 bf = *(const bf16x8*)(Bt + (size_t)(fc * 16 + l15) * KSTR + kb);
            acc[fc] = __builtin_amdgcn_mfma_f32_16x16x32_bf16(af, bf, acc[fc], 0, 0, 0);
        }
    }

    float rs[4] = {0.f, 0.f, 0.f, 0.f};
    #pragma unroll
    for (int fc = 0; fc < 19; fc++) {
        int col = fc * 16 + l15;
        bool valid = col < EMB;
        float bs = valid ? bias[col] : 0.f;
        #pragma unroll
        for (int r = 0; r < 4; r++) {
            float v = 0.f;
            if (valid) v = acc[fc][r] + bs + bf2f(Res[(size_t)(m0 + lg * 4 + r) * EMB + col]);
            acc[fc][r] = v;
            rs[r] += v;
        }
    }
    #pragma unroll
    for (int r = 0; r < 4; r++)
        #pragma unroll
        for (int off = 1; off < 16; off <<= 1)
            rs[r] += __shfl_xor(rs[r], off);
    float mean[4], invv[4];
    #pragma unroll
    for (int r = 0; r < 4; r++) mean[r] = rs[r] * (1.f / EMB);

    float rq[4] = {0.f, 0.f, 0.f, 0.f};
    #pragma unroll
    for (int fc = 0; fc < 19; fc++) {
        int col = fc * 16 + l15;
        if (col < EMB) {
            #pragma unroll
            for (int r = 0; r < 4; r++) {
                float d = acc[fc][r] - mean[r];
                rq[r] += d * d;
            }
        }
    }
    #pragma unroll
    for (int r = 0; r < 4; r++) {
        #pragma unroll
        for (int off = 1; off < 16; off <<= 1)
            rq[r] += __shfl_xor(rq[r], off);
        float stdv = sqrtf(rq[r] * (1.f / (EMB - 1)));
        invv[r] = 1.f / (stdv + 1e-6f);
    }

    if (!MIX) {
        #pragma unroll
        for (int fc = 0; fc < 19; fc++) {
            int col = fc * 16 + l15;
            if (col >= EMB) continue;
            float gv = g[col], bv = beta[col];
            #pragma unroll
            for (int r = 0; r < 4; r++) {
                float y = gv * (acc[fc][r] - mean[r]) * invv[r] + bv;
                Y[(size_t)(m0 + lg * 4 + r) * EMB + col] = __float2bfloat16(y);
            }
        }
    } else {
        float mx = mixer[0];
        float mval[4];
        #pragma unroll
        for (int r = 0; r < 4; r++) mval[r] = mall[m0 + lg * 4 + r];
        float sq[4] = {0.f, 0.f, 0.f, 0.f};
        #pragma unroll
        for (int fc = 0; fc < 19; fc++) {
            int col = fc * 16 + l15;
            bool valid = col < EMB;
            float gv = valid ? g[col] : 0.f;
            float bv = valid ? beta[col] : 0.f;
            #pragma unroll
            for (int r = 0; r < 4; r++) {
                float v = 0.f;
                if (valid) {
                    float ln = gv * (acc[fc][r] - mean[r]) * invv[r] + bv;
                    float xo = bf2f(Xorig[(size_t)(m0 + lg * 4 + r) * EMB + col]);
                    v = (mx * xo + (1.f - mx) * ln) * mval[r];
                }
                acc[fc][r] = v;
                sq[r] += v * v;
            }
        }
        #pragma unroll
        for (int r = 0; r < 4; r++) {
            #pragma unroll
            for (int off = 1; off < 16; off <<= 1)
                sq[r] += __shfl_xor(sq[r], off);
            sq[r] = 1.f / (sqrtf(sq[r]) + 1e-13f);
        }
        #pragma unroll
        for (int fc = 0; fc < 19; fc++) {
            int col = fc * 16 + l15;
            if (col >= EMB) continue;
            #pragma unroll
            for (int r = 0; r < 4; r++) {
                Y[(size_t)(m0 + lg * 4 + r) * EMB + col] = __float2bfloat16(acc[fc][r] * sq[r]);
            }
        }
    }
}

// ---------------- batched MFMA cos GEMM: Cos[b] = Qn[b] @ Dn[b]^T (bf16 out) -------------
__global__ __launch_bounds__(256) void cos_mfma(const __hip_bfloat16* __restrict__ Qn,
                                                const __hip_bfloat16* __restrict__ Dn,
                                                __hip_bfloat16* __restrict__ Cos) {
    __shared__ __align__(16) __hip_bfloat16 As[64][40];
    __shared__ __align__(16) __hip_bfloat16 Bs[64][40];
    const int b = blockIdx.y;
    const int n0 = blockIdx.x * 64;
    const int tid = threadIdx.x;
    const int lane = tid & 63;
    const int wv = tid >> 6;
    const int wm = wv >> 1, wn = wv & 1;
    const int l15 = lane & 15, lg = lane >> 4;
    const int srow = tid >> 2, sk8 = (tid & 3) * 8;
    f32x4 acc[2][2] = {};
    const int NS = (EMB + 31) >> 5;   // 10
    const __hip_bfloat16* arow = Qn + ((size_t)b * LQ + srow) * EMB;
    const __hip_bfloat16* brow = Dn + ((size_t)b * LD + n0 + srow) * EMB;

    for (int s = 0; s < NS; s++) {
        const int gk = (s << 5) + sk8;
        if (s) __syncthreads();
        stage_row8(arow, true, EMB, gk, &As[srow][sk8]);
        stage_row8(brow, true, EMB, gk, &Bs[srow][sk8]);
        __syncthreads();
        bf16x8 af0 = *(const bf16x8*)&As[wm * 32 + l15][lg * 8];
        bf16x8 af1 = *(const bf16x8*)&As[wm * 32 + 16 + l15][lg * 8];
        bf16x8 bf0 = *(const bf16x8*)&Bs[wn * 32 + l15][lg * 8];
        bf16x8 bf1 = *(const bf16x8*)&Bs[wn * 32 + 16 + l15][lg * 8];
        acc[0][0] = __builtin_amdgcn_mfma_f32_16x16x32_bf16(af0, bf0, acc[0][0], 0, 0, 0);
        acc[0][1] = __builtin_amdgcn_mfma_f32_16x16x32_bf16(af0, bf1, acc[0][1], 0, 0, 0);
        acc[1][0] = __builtin_amdgcn_mfma_f32_16x16x32_bf16(af1, bf0, acc[1][0], 0, 0, 0);
        acc[1][1] = __builtin_amdgcn_mfma_f32_16x16x32_bf16(af1, bf1, acc[1][1], 0, 0, 0);
    }

    __hip_bfloat16* cb = Cos + (size_t)b * LQ * LD;
    #pragma unroll
    for (int fc = 0; fc < 2; fc++) {
        int col = n0 + wn * 32 + fc * 16 + l15;
        #pragma unroll
        for (int fr = 0; fr < 2; fr++) {
            int rbase = wm * 32 + fr * 16 + lg * 4;
            #pragma unroll
            for (int r = 0; r < 4; r++) {
                cb[(size_t)(rbase + r) * LD + col] = __float2bfloat16(acc[fr][fc][r]);
            }
        }
    }
}

// ---------------- attention body (templated), smem carved by caller ----------------
template <int T, int RPB, int KS>
__device__ __forceinline__ void attn_body(const __hip_bfloat16* __restrict__ cseg,
                                          const float* __restrict__ mask,
                                          __hip_bfloat16* __restrict__ oseg,
                                          int bh, int rb, char* smem) {
    constexpr int BLK = 512;
    float4* Ks = (float4*)smem;
    float4* Vs = Ks + T;
    float* part = (float*)(Vs + T);
    float* nmask_s = part + RPB * 5 * (KS - 1);
    const int b = bh / NH, h = bh % NH;
    const int tid = threadIdx.x;
    const __hip_bfloat16* base = cseg + (size_t)b * T * 96;

    if (tid == 0) *nmask_s = 0.f;
    __syncthreads();
    float lnm = 0.f;
    for (int j = tid; j < T; j += BLK) {
        float m = mask[b * T + j];
        float4 kv = bf4_to_f4(base + (size_t)j * 96 + ATTD + h * 4);
        float4 vv = bf4_to_f4(base + (size_t)j * 96 + 2 * ATTD + h * 4);
        kv.x *= m; kv.y *= m; kv.z *= m; kv.w *= m;
        vv.x *= m; vv.y *= m; vv.z *= m; vv.w *= m;
        Ks[j] = kv;
        Vs[j] = vv;
        lnm += 1.f - m;
    }
    lnm = wave_sum(lnm);
    if ((tid & 63) == 0 && lnm != 0.f) atomicAdd(nmask_s, lnm);
    __syncthreads();

    const int r = rb * RPB + (tid % RPB);
    const int ks = tid / RPB;
    const float inv_scale = 0.16439898730535729f;  // 1/sqrt(37)
    float4 qv = bf4_to_f4(base + (size_t)r * 96 + h * 4);
    qv.x *= inv_scale; qv.y *= inv_scale; qv.z *= inv_scale; qv.w *= inv_scale;

    float Sall = 0.f, ox = 0.f, oy = 0.f, oz = 0.f, ow = 0.f;
    constexpr int KC = T / KS;
    const int k0 = ks * KC;
    #pragma unroll 4
    for (int k = k0; k < k0 + KC; k++) {
        float4 kv = Ks[k];
        float4 vv = Vs[k];
        float s = fmaf(qv.x, kv.x, fmaf(qv.y, kv.y, fmaf(qv.z, kv.z, qv.w * kv.w)));
        float e = __expf(s);
        Sall += e;
        ox = fmaf(e, vv.x, ox);
        oy = fmaf(e, vv.y, oy);
        oz = fmaf(e, vv.z, oz);
        ow = fmaf(e, vv.w, ow);
    }
    if (ks > 0) {
        float* p = &part[((ks - 1) * RPB + (tid % RPB)) * 5];
        p[0] = Sall; p[1] = ox; p[2] = oy; p[3] = oz; p[4] = ow;
    }
    __syncthreads();
    if (ks == 0) {
        #pragma unroll
        for (int s2 = 0; s2 < KS - 1; s2++) {
            const float* p = &part[(s2 * RPB + r - rb * RPB) * 5];
            Sall += p[0]; ox += p[1]; oy += p[2]; oz += p[3]; ow += p[4];
        }
        float Sm = Sall - *nmask_s;
        float inv = 1.f / (Sm + 1e-13f * Sall);
        __hip_bfloat16* op = oseg + (size_t)(b * T + r) * ATTD + h * 4;
        op[0] = __float2bfloat16(ox * inv);
        op[1] = __float2bfloat16(oy * inv);
        op[2] = __float2bfloat16(oz * inv);
        op[3] = __float2bfloat16(ow * inv);
    }
}

// ---------------- merged q+d attention: blocks [0,256) = q, [256,1280) = d ----------------
__global__ __launch_bounds__(512) void attn_both(const __hip_bfloat16* __restrict__ cbf,
                                                 const float* __restrict__ mask_q,
                                                 const float* __restrict__ mask_d,
                                                 __hip_bfloat16* __restrict__ o32) {
    __shared__ __align__(16) char smem[24576];
    int blk = blockIdx.x;
    if (blk < BATCH * NH) {
        attn_body<LQ, 64, 8>(cbf, mask_q, o32, blk, 0, smem);
    } else {
        int bid = blk - BATCH * NH;
        attn_body<LD, 128, 4>(cbf + (size_t)MQ * 96, mask_d, o32 + (size_t)MQ * ATTD,
                              bid >> 2, bid & 3, smem);
    }
}

// ---------------- kernel pooling + per-wave final contribution (no fences) ---------------
// Each (b,qi) wave computes its full 21-kernel pooled row, folds log/mask/scaler/dense_w
// locally, and adds ONE float to out[b] via atomicAdd (device-scope by default).
__global__ __launch_bounds__(256) void pool_kernel(const __hip_bfloat16* __restrict__ Cos,
                                                   const float* __restrict__ mask_q,
                                                   const float* __restrict__ mask_d,
                                                   const float* __restrict__ nn_scaler,
                                                   const float* __restrict__ dense_w,
                                                   float* __restrict__ out) {
    int wid = (blockIdx.x * 256 + threadIdx.x) >> 6;
    int lane = threadIdx.x & 63;
    int b = wid >> 6, qi = wid & 63;
    const __hip_bfloat16* crow = Cos + ((size_t)b * LQ + qi) * LD;
    const float* md = mask_d + b * LD;
    float acc[NK];
    #pragma unroll
    for (int k = 0; k < NK; k++) acc[k] = 0.f;
    #pragma unroll
    for (int rr = 0; rr < LD / 64; rr++) {
        int dj = rr * 64 + lane;
        float m = md[dj];
        if (m != 0.f) {
            float cv = bf2f(crow[dj]);
            float d0 = cv - 1.0f;
            acc[0] += __expf(d0 * d0 * -500000.0f);
            #pragma unroll
            for (int g = 0; g < 4; g++) {
                float mu_a = 0.95f - 0.5f * g;
                float dc = cv - mu_a;
                float t = __expf(dc * dc * -50.0f);
                float r = __expf(fmaf(-10.0f, dc, -0.5f));
                #pragma unroll
                for (int j = 0; j < 5; j++) {
                    acc[1 + 5 * g + j] += t;
                    t *= r;
                    r *= 0.36787944117144233f;   // e^-1
                }
            }
        }
    }
    float part = 0.f;
    #pragma unroll
    for (int k = 0; k < NK; k++) {
        float s = wave_sum(acc[k]);
        part = fmaf(log2f(fmaxf(s, 1e-10f)), dense_w[k], part);
    }
    if (lane == 0) {
        float mq = mask_q[b * LQ + qi];
        float ns = nn_scaler[0];
        atomicAdd(&out[b], part * ns * mq);
    }
}

extern "C" void kernel_launch(void* const* d_in, const int* in_sizes, int n_in,
                              void* d_out, int out_size, void* d_ws, size_t ws_size,
                              hipStream_t stream) {
    (void)in_sizes; (void)n_in; (void)out_size; (void)ws_size;
    const float* q_embed  = (const float*)d_in[0];
    const float* d_embed  = (const float*)d_in[1];
    const float* mask_q   = (const float*)d_in[2];
    const float* mask_d   = (const float*)d_in[3];
    const float* mixer    = (const float*)d_in[4];
    const float* nn_scaler= (const float*)d_in[5];
    const float* ff_w1    = (const float*)d_in[6];
    const float* ff_b1    = (const float*)d_in[7];
    const float* ff_w2    = (const float*)d_in[8];
    const float* ff_b2    = (const float*)d_in[9];
    const float* ln1_g    = (const float*)d_in[10];
    const float* ln1_b    = (const float*)d_in[11];
    const float* att_w    = (const float*)d_in[12];
    const float* att_b    = (const float*)d_in[13];
    const float* out_w    = (const float*)d_in[14];
    const float* out_b    = (const float*)d_in[15];
    const float* ln2_g    = (const float*)d_in[16];
    const float* ln2_b    = (const float*)d_in[17];
    const float* dense_w  = (const float*)d_in[18];
    float* out = (float*)d_out;

    // ---------------- workspace layout ----------------
    float* ws   = (float*)d_ws;
    float* mall = ws;                         // 18,432
    __hip_bfloat16* cosbf = (__hip_bfloat16*)(mall + MALL);   // 1,048,576 bf16
    __hip_bfloat16* xbf   = cosbf + (size_t)BATCH * LQ * LD;  // MALL*EMB masked embeddings
    __hip_bfloat16* xcbf  = xbf  + (size_t)MALL * EMB;        // layer-0 output
    __hip_bfloat16* qdn   = xcbf + (size_t)MALL * EMB;        // layer-1 fused LN2+mixnorm out
    __hip_bfloat16* hbf   = qdn  + (size_t)MALL * EMB;        // LN1 out
    __hip_bfloat16* t1bf  = hbf  + (size_t)MALL * EMB;        // MALL*128 (stride-128, zero-pad)
    __hip_bfloat16* cbf   = t1bf + (size_t)MALL * 128;        // MALL*96
    __hip_bfloat16* o32bf = cbf  + (size_t)MALL * 96;         // MALL*ATTD
    __hip_bfloat16* w1t   = o32bf + (size_t)MALL * ATTD;      // 2*100*300
    __hip_bfloat16* w2t   = w1t + 2 * FFH * EMB;              // 2*320*128 (padded)
    __hip_bfloat16* awt   = w2t + 2 * 320 * 128;              // 2*96*300
    __hip_bfloat16* owt   = awt + 2 * 96 * EMB;               // 2*320*32 (padded)

    // 0. fused prep: masked embeddings + masks + all weights + out zero
    const int PREP_N = MALL * (EMB / 4) + 2 * EMB * FFH + 2 * 320 * 128 + 2 * EMB * 96
                     + 2 * 320 * 32 + BATCH;
    prep_all<<<(PREP_N + 255) / 256, 256, 0, stream>>>(
        q_embed, d_embed, mask_q, mask_d, ff_w1, ff_w2, att_w, out_w,
        xbf, mall, w1t, w2t, awt, owt, out);

    // 1. merged encoder; layer-1 OUT+LN2 also folds mix+normalize
    const __hip_bfloat16* xcur = xbf;
    for (int l = 0; l < 2; l++) {
        // FF1: relu(x @ w1 + b1) -> t1bf (stride 128, cols 100..127 zeroed)
        gemm_mfma<true><<<dim3(2, MALL / 64), 256, 0, stream>>>(
            xcur, w1t + (size_t)l * FFH * EMB, ff_b1 + l * FFH, t1bf, MALL, FFH, 128, EMB);
        // FF2 + residual(x) + LN1 -> hbf   (direct, K=128 padded)
        gemm_ln_direct<4, 128, 128, false><<<MALL / 64, 256, 0, stream>>>(
            t1bf, w2t + (size_t)l * 320 * 128, ff_b2 + l * EMB, xcur,
            ln1_g + l * EMB, ln1_b + l * EMB, hbf, nullptr, nullptr, nullptr);
        // ATT: h @ att_w + att_b -> cbf
        gemm_mfma<false><<<dim3(2, MALL / 64), 256, 0, stream>>>(
            hbf, awt + (size_t)l * 96 * EMB, att_b + l * 96, cbf, MALL, 96, 96, EMB);
        // attention (q + d merged) -> o32bf
        attn_both<<<BATCH * NH + BATCH * NH * (LD / 128), 512, 0, stream>>>(
            cbf, mask_q, mask_d, o32bf);
        // OUT + residual(h) + LN2 (-> xcbf for l=0; + mix/normalize -> qdn for l=1)
        if (l == 0) {
            gemm_ln_direct<1, 32, 32, false><<<MALL / 64, 256, 0, stream>>>(
                o32bf, owt, out_b, hbf, ln2_g, ln2_b, xcbf, nullptr, nullptr, nullptr);
            xcur = xcbf;
        } else {
            gemm_ln_direct<1, 32, 32, true><<<MALL / 64, 256, 0, stream>>>(
                o32bf, owt + (size_t)320 * 32, out_b + EMB, hbf,
                ln2_g + EMB, ln2_b + EMB, qdn, xbf, mall, mixer);
        }
    }

    // 2. cosine matrix via MFMA -> cosbf (bf16)
    cos_mfma<<<dim3(LD / 64, BATCH), 256, 0, stream>>>(qdn, qdn + (size_t)MQ * EMB, cosbf);

    // 3. kernel pooling + per-wave final contribution (atomicAdd to out)
    pool_kernel<<<(BATCH * LQ) / 4, 256, 0, stream>>>(cosbf, mask_q, mask_d, nn_scaler,
                                                      dense_w, out);
}

// Round 21
// 232.498 us; speedup vs baseline: 1.0286x; 1.0286x over previous
//
#include <hip/hip_runtime.h>
#include <hip/hip_bf16.h>

// Problem constants
#define BATCH 32
#define LQ 64
#define LD 512
#define EMB 300
#define FFH 100
#define ATTD 32
#define NH 8
#define NK 21
#define MQ (BATCH * LQ)          // 2048 query tokens
#define MD (BATCH * LD)          // 16384 doc tokens
#define MALL (MQ + MD)           // 18432 merged tokens

typedef __attribute__((ext_vector_type(8))) short bf16x8;
typedef __attribute__((ext_vector_type(4))) float f32x4;

__device__ __forceinline__ float wave_sum(float v) {
    #pragma unroll
    for (int off = 32; off > 0; off >>= 1) v += __shfl_xor(v, off);
    return v;
}

__device__ __forceinline__ float bf2f(__hip_bfloat16 h) { return __bfloat162float(h); }

// 4 consecutive bf16 -> float4 (8B-aligned source)
__device__ __forceinline__ float4 bf4_to_f4(const __hip_bfloat16* p) {
    uint2 u = *(const uint2*)p;
    float4 f;
    f.x = __uint_as_float((u.x & 0xffffu) << 16);
    f.y = __uint_as_float(u.x & 0xffff0000u);
    f.z = __uint_as_float((u.y & 0xffffu) << 16);
    f.w = __uint_as_float(u.y & 0xffff0000u);
    return f;
}

__device__ __forceinline__ unsigned short f2bfu(float x) {
    __hip_bfloat16 h = __float2bfloat16(x);
    return *(unsigned short*)&h;
}

// ---------------- fused prep: masked embeddings (float4 reads) + masks + all weights -----
__global__ void prep_all(const float* __restrict__ qe, const float* __restrict__ de,
                         const float* __restrict__ mq, const float* __restrict__ md,
                         const float* __restrict__ w1, const float* __restrict__ w2,
                         const float* __restrict__ aw, const float* __restrict__ ow,
                         __hip_bfloat16* __restrict__ xbf, float* __restrict__ mall,
                         __hip_bfloat16* __restrict__ w1t, __hip_bfloat16* __restrict__ w2t,
                         __hip_bfloat16* __restrict__ awt, __hip_bfloat16* __restrict__ owt) {
    int i = blockIdx.x * blockDim.x + threadIdx.x;
    const int NQ4 = MALL * (EMB / 4);             // 1,382,400 float4 chunks
    if (i < NQ4) {
        int tok = i / (EMB / 4), c4 = (i % (EMB / 4)) * 4;
        float m;
        float4 v;
        if (tok < MQ) {
            m = mq[tok];
            v = *(const float4*)(qe + (size_t)tok * EMB + c4);
        } else {
            m = md[tok - MQ];
            v = *(const float4*)(de + (size_t)(tok - MQ) * EMB + c4);
        }
        uint2 u;
        u.x = (unsigned)f2bfu(v.x * m) | ((unsigned)f2bfu(v.y * m) << 16);
        u.y = (unsigned)f2bfu(v.z * m) | ((unsigned)f2bfu(v.w * m) << 16);
        *(uint2*)(xbf + (size_t)tok * EMB + c4) = u;
        if (c4 == 0) mall[tok] = m;
        return;
    }
    int j = i - NQ4;
    if (j < 2 * EMB * FFH) {                      // w1t: w1[l][k][n] -> [l][n][k]
        int l = j / (EMB * FFH), r = j % (EMB * FFH);
        int k = r / FFH, n = r % FFH;
        w1t[(size_t)l * FFH * EMB + (size_t)n * EMB + k] = __float2bfloat16(w1[j]);
        return;
    }
    j -= 2 * EMB * FFH;
    if (j < 2 * 320 * 128) {                      // w2t zero-padded [l][320][128]
        int l = j / (320 * 128), r = j % (320 * 128);
        int n = r / 128, k = r % 128;
        float v = (n < EMB && k < FFH) ? w2[(size_t)l * FFH * EMB + (size_t)k * EMB + n] : 0.f;
        w2t[j] = __float2bfloat16(v);
        return;
    }
    j -= 2 * 320 * 128;
    if (j < 2 * EMB * 96) {                       // awt: aw[l][k][n] -> [l][n][k]
        int l = j / (EMB * 96), r = j % (EMB * 96);
        int k = r / 96, n = r % 96;
        awt[(size_t)l * 96 * EMB + (size_t)n * EMB + k] = __float2bfloat16(aw[j]);
        return;
    }
    j -= 2 * EMB * 96;
    if (j < 2 * 320 * 32) {                       // owt zero-padded [l][320][32]
        int l = j / (320 * 32), r = j % (320 * 32);
        int n = r / 32, k = r % 32;
        float v = (n < EMB) ? ow[(size_t)l * ATTD * EMB + (size_t)k * EMB + n] : 0.f;
        owt[j] = __float2bfloat16(v);
    }
}

// ---------------- shared staging helper: 8 bf16 of one row ----------------
__device__ __forceinline__ void stage_row8(const __hip_bfloat16* __restrict__ src, bool rowvalid,
                                           int K, int gk, __hip_bfloat16* dst) {
    if (rowvalid && gk + 8 <= K) {
        const uint2* p = (const uint2*)(src + gk);
        uint2 a = p[0], b = p[1];
        *(uint2*)dst = a;
        *(uint2*)(dst + 4) = b;
    } else {
        #pragma unroll
        for (int j = 0; j < 8; j++)
            dst[j] = (rowvalid && gk + j < K) ? src[gk + j] : __float2bfloat16(0.f);
    }
}

// ---------------- MFMA bf16 GEMM: Cb[M,Ns] = A[M,K] @ Bt[Nr,K]^T + bias (+relu) ---------
template <bool RELU>
__global__ __launch_bounds__(256) void gemm_mfma(const __hip_bfloat16* __restrict__ A,
                                                 const __hip_bfloat16* __restrict__ Bt,
                                                 const float* __restrict__ bias,
                                                 __hip_bfloat16* __restrict__ Cb,
                                                 int M, int Nr, int Ns, int K) {
    __shared__ __align__(16) __hip_bfloat16 As[64][40];
    __shared__ __align__(16) __hip_bfloat16 Bs[64][40];
    const int tid = threadIdx.x;
    const int m0 = blockIdx.y * 64, n0 = blockIdx.x * 64;
    const int lane = tid & 63;
    const int wv = tid >> 6;
    const int wm = wv >> 1, wn = wv & 1;
    const int l15 = lane & 15, lg = lane >> 4;
    const int srow = tid >> 2, sk8 = (tid & 3) * 8;
    f32x4 acc[2][2] = {};
    const int NS = (K + 31) >> 5;
    const __hip_bfloat16* arow = A + (size_t)(m0 + srow) * K;
    const bool bvalid = (n0 + srow) < Nr;
    const __hip_bfloat16* brow = Bt + (size_t)(n0 + srow) * K;

    for (int s = 0; s < NS; s++) {
        const int gk = (s << 5) + sk8;
        if (s) __syncthreads();
        stage_row8(arow, true, K, gk, &As[srow][sk8]);
        stage_row8(brow, bvalid, K, gk, &Bs[srow][sk8]);
        __syncthreads();
        bf16x8 af0 = *(const bf16x8*)&As[wm * 32 + l15][lg * 8];
        bf16x8 af1 = *(const bf16x8*)&As[wm * 32 + 16 + l15][lg * 8];
        bf16x8 bf0 = *(const bf16x8*)&Bs[wn * 32 + l15][lg * 8];
        bf16x8 bf1 = *(const bf16x8*)&Bs[wn * 32 + 16 + l15][lg * 8];
        acc[0][0] = __builtin_amdgcn_mfma_f32_16x16x32_bf16(af0, bf0, acc[0][0], 0, 0, 0);
        acc[0][1] = __builtin_amdgcn_mfma_f32_16x16x32_bf16(af0, bf1, acc[0][1], 0, 0, 0);
        acc[1][0] = __builtin_amdgcn_mfma_f32_16x16x32_bf16(af1, bf0, acc[1][0], 0, 0, 0);
        acc[1][1] = __builtin_amdgcn_mfma_f32_16x16x32_bf16(af1, bf1, acc[1][1], 0, 0, 0);
    }

    #pragma unroll
    for (int fc = 0; fc < 2; fc++) {
        int col = n0 + wn * 32 + fc * 16 + l15;
        if (col >= Ns) continue;
        float bs = (col < Nr) ? bias[col] : 0.f;
        #pragma unroll
        for (int fr = 0; fr < 2; fr++) {
            int rbase = m0 + wm * 32 + fr * 16 + lg * 4;
            #pragma unroll
            for (int r = 0; r < 4; r++) {
                float v = acc[fr][fc][r] + bs;
                if (RELU) v = fmaxf(v, 0.f);
                Cb[(size_t)(rbase + r) * Ns + col] = __float2bfloat16(v);
            }
        }
    }
}

// ---------------- DIRECT-OPERAND GEMM + residual + LayerNorm (N = 300, no LDS) ----------
// MIX: additionally fold mix+L2-normalize: out = normalize((mx*xorig + (1-mx)*LN)*mask).
template <int NSTEP, int KSTR, int ASTR, bool MIX>
__global__ __launch_bounds__(256) void gemm_ln_direct(const __hip_bfloat16* __restrict__ A,
                                                      const __hip_bfloat16* __restrict__ Bt,
                                                      const float* __restrict__ bias,
                                                      const __hip_bfloat16* __restrict__ Res,
                                                      const float* __restrict__ g,
                                                      const float* __restrict__ beta,
                                                      __hip_bfloat16* __restrict__ Y,
                                                      const __hip_bfloat16* __restrict__ Xorig,
                                                      const float* __restrict__ mall,
                                                      const float* __restrict__ mixer) {
    const int tid = threadIdx.x;
    const int wv = tid >> 6;
    const int lane = tid & 63;
    const int l15 = lane & 15, lg = lane >> 4;
    const int m0 = blockIdx.x * 64 + wv * 16;

    f32x4 acc[19];
    #pragma unroll
    for (int fc = 0; fc < 19; fc++) acc[fc] = (f32x4){0.f, 0.f, 0.f, 0.f};

    #pragma unroll
    for (int ks = 0; ks < NSTEP; ks++) {
        const int kb = ks * 32 + lg * 8;
        bf16x8 af = *(const bf16x8*)(A + (size_t)(m0 + l15) * ASTR + kb);
        #pragma unroll
        for (int fc = 0; fc < 19; fc++) {
            bf16x8 bf = *(const bf16x8*)(Bt + (size_t)(fc * 16 + l15) * KSTR + kb);
            acc[fc] = __builtin_amdgcn_mfma_f32_16x16x32_bf16(af, bf, acc[fc], 0, 0, 0);
        }
    }

    float rs[4] = {0.f, 0.f, 0.f, 0.f};
    #pragma unroll
    for (int fc = 0; fc < 19; fc++) {
        int col = fc * 16 + l15;
        bool valid = col < EMB;
        float bs = valid ? bias[col] : 0.f;
        #pragma unroll
        for (int r = 0; r < 4; r++) {
            float v = 0.f;
            if (valid) v = acc[fc][r] + bs + bf2f(Res[(size_t)(m0 + lg * 4 + r) * EMB + col]);
            acc[fc][r] = v;
            rs[r] += v;
        }
    }
    #pragma unroll
    for (int r = 0; r < 4; r++)
        #pragma unroll
        for (int off = 1; off < 16; off <<= 1)
            rs[r] += __shfl_xor(rs[r], off);
    float mean[4], invv[4];
    #pragma unroll
    for (int r = 0; r < 4; r++) mean[r] = rs[r] * (1.f / EMB);

    float rq[4] = {0.f, 0.f, 0.f, 0.f};
    #pragma unroll
    for (int fc = 0; fc < 19; fc++) {
        int col = fc * 16 + l15;
        if (col < EMB) {
            #pragma unroll
            for (int r = 0; r < 4; r++) {
                float d = acc[fc][r] - mean[r];
                rq[r] += d * d;
            }
        }
    }
    #pragma unroll
    for (int r = 0; r < 4; r++) {
        #pragma unroll
        for (int off = 1; off < 16; off <<= 1)
            rq[r] += __shfl_xor(rq[r], off);
        float stdv = sqrtf(rq[r] * (1.f / (EMB - 1)));
        invv[r] = 1.f / (stdv + 1e-6f);
    }

    if (!MIX) {
        #pragma unroll
        for (int fc = 0; fc < 19; fc++) {
            int col = fc * 16 + l15;
            if (col >= EMB) continue;
            float gv = g[col], bv = beta[col];
            #pragma unroll
            for (int r = 0; r < 4; r++) {
                float y = gv * (acc[fc][r] - mean[r]) * invv[r] + bv;
                Y[(size_t)(m0 + lg * 4 + r) * EMB + col] = __float2bfloat16(y);
            }
        }
    } else {
        float mx = mixer[0];
        float mval[4];
        #pragma unroll
        for (int r = 0; r < 4; r++) mval[r] = mall[m0 + lg * 4 + r];
        float sq[4] = {0.f, 0.f, 0.f, 0.f};
        #pragma unroll
        for (int fc = 0; fc < 19; fc++) {
            int col = fc * 16 + l15;
            bool valid = col < EMB;
            float gv = valid ? g[col] : 0.f;
            float bv = valid ? beta[col] : 0.f;
            #pragma unroll
            for (int r = 0; r < 4; r++) {
                float v = 0.f;
                if (valid) {
                    float ln = gv * (acc[fc][r] - mean[r]) * invv[r] + bv;
                    float xo = bf2f(Xorig[(size_t)(m0 + lg * 4 + r) * EMB + col]);
                    v = (mx * xo + (1.f - mx) * ln) * mval[r];
                }
                acc[fc][r] = v;
                sq[r] += v * v;
            }
        }
        #pragma unroll
        for (int r = 0; r < 4; r++) {
            #pragma unroll
            for (int off = 1; off < 16; off <<= 1)
                sq[r] += __shfl_xor(sq[r], off);
            sq[r] = 1.f / (sqrtf(sq[r]) + 1e-13f);
        }
        #pragma unroll
        for (int fc = 0; fc < 19; fc++) {
            int col = fc * 16 + l15;
            if (col >= EMB) continue;
            #pragma unroll
            for (int r = 0; r < 4; r++) {
                Y[(size_t)(m0 + lg * 4 + r) * EMB + col] = __float2bfloat16(acc[fc][r] * sq[r]);
            }
        }
    }
}

// ---------------- batched MFMA cos GEMM: Cos[b] = Qn[b] @ Dn[b]^T (bf16 out) -------------
__global__ __launch_bounds__(256) void cos_mfma(const __hip_bfloat16* __restrict__ Qn,
                                                const __hip_bfloat16* __restrict__ Dn,
                                                __hip_bfloat16* __restrict__ Cos) {
    __shared__ __align__(16) __hip_bfloat16 As[64][40];
    __shared__ __align__(16) __hip_bfloat16 Bs[64][40];
    const int b = blockIdx.y;
    const int n0 = blockIdx.x * 64;
    const int tid = threadIdx.x;
    const int lane = tid & 63;
    const int wv = tid >> 6;
    const int wm = wv >> 1, wn = wv & 1;
    const int l15 = lane & 15, lg = lane >> 4;
    const int srow = tid >> 2, sk8 = (tid & 3) * 8;
    f32x4 acc[2][2] = {};
    const int NS = (EMB + 31) >> 5;   // 10
    const __hip_bfloat16* arow = Qn + ((size_t)b * LQ + srow) * EMB;
    const __hip_bfloat16* brow = Dn + ((size_t)b * LD + n0 + srow) * EMB;

    for (int s = 0; s < NS; s++) {
        const int gk = (s << 5) + sk8;
        if (s) __syncthreads();
        stage_row8(arow, true, EMB, gk, &As[srow][sk8]);
        stage_row8(brow, true, EMB, gk, &Bs[srow][sk8]);
        __syncthreads();
        bf16x8 af0 = *(const bf16x8*)&As[wm * 32 + l15][lg * 8];
        bf16x8 af1 = *(const bf16x8*)&As[wm * 32 + 16 + l15][lg * 8];
        bf16x8 bf0 = *(const bf16x8*)&Bs[wn * 32 + l15][lg * 8];
        bf16x8 bf1 = *(const bf16x8*)&Bs[wn * 32 + 16 + l15][lg * 8];
        acc[0][0] = __builtin_amdgcn_mfma_f32_16x16x32_bf16(af0, bf0, acc[0][0], 0, 0, 0);
        acc[0][1] = __builtin_amdgcn_mfma_f32_16x16x32_bf16(af0, bf1, acc[0][1], 0, 0, 0);
        acc[1][0] = __builtin_amdgcn_mfma_f32_16x16x32_bf16(af1, bf0, acc[1][0], 0, 0, 0);
        acc[1][1] = __builtin_amdgcn_mfma_f32_16x16x32_bf16(af1, bf1, acc[1][1], 0, 0, 0);
    }

    __hip_bfloat16* cb = Cos + (size_t)b * LQ * LD;
    #pragma unroll
    for (int fc = 0; fc < 2; fc++) {
        int col = n0 + wn * 32 + fc * 16 + l15;
        #pragma unroll
        for (int fr = 0; fr < 2; fr++) {
            int rbase = wm * 32 + fr * 16 + lg * 4;
            #pragma unroll
            for (int r = 0; r < 4; r++) {
                cb[(size_t)(rbase + r) * LD + col] = __float2bfloat16(acc[fr][fc][r]);
            }
        }
    }
}

// ---------------- attention body (templated), smem carved by caller ----------------
template <int T, int RPB, int KS>
__device__ __forceinline__ void attn_body(const __hip_bfloat16* __restrict__ cseg,
                                          const float* __restrict__ mask,
                                          __hip_bfloat16* __restrict__ oseg,
                                          int bh, int rb, char* smem) {
    constexpr int BLK = 512;
    float4* Ks = (float4*)smem;
    float4* Vs = Ks + T;
    float* part = (float*)(Vs + T);
    float* nmask_s = part + RPB * 5 * (KS - 1);
    const int b = bh / NH, h = bh % NH;
    const int tid = threadIdx.x;
    const __hip_bfloat16* base = cseg + (size_t)b * T * 96;

    if (tid == 0) *nmask_s = 0.f;
    __syncthreads();
    float lnm = 0.f;
    for (int j = tid; j < T; j += BLK) {
        float m = mask[b * T + j];
        float4 kv = bf4_to_f4(base + (size_t)j * 96 + ATTD + h * 4);
        float4 vv = bf4_to_f4(base + (size_t)j * 96 + 2 * ATTD + h * 4);
        kv.x *= m; kv.y *= m; kv.z *= m; kv.w *= m;
        vv.x *= m; vv.y *= m; vv.z *= m; vv.w *= m;
        Ks[j] = kv;
        Vs[j] = vv;
        lnm += 1.f - m;
    }
    lnm = wave_sum(lnm);
    if ((tid & 63) == 0 && lnm != 0.f) atomicAdd(nmask_s, lnm);
    __syncthreads();

    const int r = rb * RPB + (tid % RPB);
    const int ks = tid / RPB;
    const float inv_scale = 0.16439898730535729f;  // 1/sqrt(37)
    float4 qv = bf4_to_f4(base + (size_t)r * 96 + h * 4);
    qv.x *= inv_scale; qv.y *= inv_scale; qv.z *= inv_scale; qv.w *= inv_scale;

    float Sall = 0.f, ox = 0.f, oy = 0.f, oz = 0.f, ow = 0.f;
    constexpr int KC = T / KS;
    const int k0 = ks * KC;
    #pragma unroll 4
    for (int k = k0; k < k0 + KC; k++) {
        float4 kv = Ks[k];
        float4 vv = Vs[k];
        float s = fmaf(qv.x, kv.x, fmaf(qv.y, kv.y, fmaf(qv.z, kv.z, qv.w * kv.w)));
        float e = __expf(s);
        Sall += e;
        ox = fmaf(e, vv.x, ox);
        oy = fmaf(e, vv.y, oy);
        oz = fmaf(e, vv.z, oz);
        ow = fmaf(e, vv.w, ow);
    }
    if (ks > 0) {
        float* p = &part[((ks - 1) * RPB + (tid % RPB)) * 5];
        p[0] = Sall; p[1] = ox; p[2] = oy; p[3] = oz; p[4] = ow;
    }
    __syncthreads();
    if (ks == 0) {
        #pragma unroll
        for (int s2 = 0; s2 < KS - 1; s2++) {
            const float* p = &part[(s2 * RPB + r - rb * RPB) * 5];
            Sall += p[0]; ox += p[1]; oy += p[2]; oz += p[3]; ow += p[4];
        }
        float Sm = Sall - *nmask_s;
        float inv = 1.f / (Sm + 1e-13f * Sall);
        __hip_bfloat16* op = oseg + (size_t)(b * T + r) * ATTD + h * 4;
        op[0] = __float2bfloat16(ox * inv);
        op[1] = __float2bfloat16(oy * inv);
        op[2] = __float2bfloat16(oz * inv);
        op[3] = __float2bfloat16(ow * inv);
    }
}

// ---------------- merged q+d attention: blocks [0,256) = q, [256,1280) = d ----------------
__global__ __launch_bounds__(512) void attn_both(const __hip_bfloat16* __restrict__ cbf,
                                                 const float* __restrict__ mask_q,
                                                 const float* __restrict__ mask_d,
                                                 __hip_bfloat16* __restrict__ o32) {
    __shared__ __align__(16) char smem[24576];
    int blk = blockIdx.x;
    if (blk < BATCH * NH) {
        attn_body<LQ, 64, 8>(cbf, mask_q, o32, blk, 0, smem);
    } else {
        int bid = blk - BATCH * NH;
        attn_body<LD, 128, 4>(cbf + (size_t)MQ * 96, mask_d, o32 + (size_t)MQ * ATTD,
                              bid >> 2, bid & 3, smem);
    }
}

// ---------------- kernel pooling (bf16 cos input) with grouped exp-recurrence ------------
__global__ __launch_bounds__(256) void pool_kernel(const __hip_bfloat16* __restrict__ Cos,
                                                   const float* __restrict__ mask_q,
                                                   const float* __restrict__ mask_d,
                                                   const float* __restrict__ nn_scaler,
                                                   float* __restrict__ lp) {
    int wid = (blockIdx.x * 256 + threadIdx.x) >> 6;
    int lane = threadIdx.x & 63;
    int b = wid >> 6, qi = wid & 63;
    const __hip_bfloat16* crow = Cos + ((size_t)b * LQ + qi) * LD;
    const float* md = mask_d + b * LD;
    float acc[NK];
    #pragma unroll
    for (int k = 0; k < NK; k++) acc[k] = 0.f;
    #pragma unroll
    for (int rr = 0; rr < LD / 64; rr++) {
        int dj = rr * 64 + lane;
        float m = md[dj];
        if (m != 0.f) {
            float cv = bf2f(crow[dj]);
            float d0 = cv - 1.0f;
            acc[0] += __expf(d0 * d0 * -500000.0f);
            #pragma unroll
            for (int g = 0; g < 4; g++) {
                float mu_a = 0.95f - 0.5f * g;
                float dc = cv - mu_a;
                float t = __expf(dc * dc * -50.0f);
                float r = __expf(fmaf(-10.0f, dc, -0.5f));
                #pragma unroll
                for (int j = 0; j < 5; j++) {
                    acc[1 + 5 * g + j] += t;
                    t *= r;
                    r *= 0.36787944117144233f;   // e^-1
                }
            }
        }
    }
    float mq = mask_q[b * LQ + qi];
    float ns = nn_scaler[0];
    #pragma unroll
    for (int k = 0; k < NK; k++) {
        float s = wave_sum(acc[k]);
        if (lane == 0) lp[((size_t)b * LQ + qi) * NK + k] = log2f(fmaxf(s, 1e-10f)) * ns * mq;
    }
}

// ---------------- final: out[b] = sum_k dense_w[k] * sum_qi lp[b,qi,k] ----------------
__global__ void final_kernel(const float* __restrict__ lp, const float* __restrict__ dense_w,
                             float* __restrict__ out) {
    int b = blockIdx.x;
    int t = threadIdx.x;  // 64 threads
    float s = 0.f;
    if (t < NK) {
        for (int qi = 0; qi < LQ; qi++) s += lp[((size_t)b * LQ + qi) * NK + t];
        s *= dense_w[t];
    }
    s = wave_sum(s);
    if (t == 0) out[b] = s;
}

extern "C" void kernel_launch(void* const* d_in, const int* in_sizes, int n_in,
                              void* d_out, int out_size, void* d_ws, size_t ws_size,
                              hipStream_t stream) {
    (void)in_sizes; (void)n_in; (void)out_size; (void)ws_size;
    const float* q_embed  = (const float*)d_in[0];
    const float* d_embed  = (const float*)d_in[1];
    const float* mask_q   = (const float*)d_in[2];
    const float* mask_d   = (const float*)d_in[3];
    const float* mixer    = (const float*)d_in[4];
    const float* nn_scaler= (const float*)d_in[5];
    const float* ff_w1    = (const float*)d_in[6];
    const float* ff_b1    = (const float*)d_in[7];
    const float* ff_w2    = (const float*)d_in[8];
    const float* ff_b2    = (const float*)d_in[9];
    const float* ln1_g    = (const float*)d_in[10];
    const float* ln1_b    = (const float*)d_in[11];
    const float* att_w    = (const float*)d_in[12];
    const float* att_b    = (const float*)d_in[13];
    const float* out_w    = (const float*)d_in[14];
    const float* out_b    = (const float*)d_in[15];
    const float* ln2_g    = (const float*)d_in[16];
    const float* ln2_b    = (const float*)d_in[17];
    const float* dense_w  = (const float*)d_in[18];
    float* out = (float*)d_out;

    // ---------------- workspace layout ----------------
    float* ws   = (float*)d_ws;
    float* lp   = ws;                         // 43,008
    float* mall = lp + 43008;                 // 18,432
    __hip_bfloat16* cosbf = (__hip_bfloat16*)(mall + MALL);   // 1,048,576 bf16
    __hip_bfloat16* xbf   = cosbf + (size_t)BATCH * LQ * LD;  // MALL*EMB masked embeddings
    __hip_bfloat16* xcbf  = xbf  + (size_t)MALL * EMB;        // layer-0 output
    __hip_bfloat16* qdn   = xcbf + (size_t)MALL * EMB;        // layer-1 fused LN2+mixnorm out
    __hip_bfloat16* hbf   = qdn  + (size_t)MALL * EMB;        // LN1 out
    __hip_bfloat16* t1bf  = hbf  + (size_t)MALL * EMB;        // MALL*128 (stride-128, zero-pad)
    __hip_bfloat16* cbf   = t1bf + (size_t)MALL * 128;        // MALL*96
    __hip_bfloat16* o32bf = cbf  + (size_t)MALL * 96;         // MALL*ATTD
    __hip_bfloat16* w1t   = o32bf + (size_t)MALL * ATTD;      // 2*100*300
    __hip_bfloat16* w2t   = w1t + 2 * FFH * EMB;              // 2*320*128 (padded)
    __hip_bfloat16* awt   = w2t + 2 * 320 * 128;              // 2*96*300
    __hip_bfloat16* owt   = awt + 2 * 96 * EMB;               // 2*320*32 (padded)

    // 0. fused prep: masked embeddings (float4 reads) + masks + all weights
    const int PREP_N = MALL * (EMB / 4) + 2 * EMB * FFH + 2 * 320 * 128 + 2 * EMB * 96 + 2 * 320 * 32;
    prep_all<<<(PREP_N + 255) / 256, 256, 0, stream>>>(
        q_embed, d_embed, mask_q, mask_d, ff_w1, ff_w2, att_w, out_w,
        xbf, mall, w1t, w2t, awt, owt);

    // 1. merged encoder; layer-1 OUT+LN2 also folds mix+normalize
    const __hip_bfloat16* xcur = xbf;
    for (int l = 0; l < 2; l++) {
        // FF1: relu(x @ w1 + b1) -> t1bf (stride 128, cols 100..127 zeroed)
        gemm_mfma<true><<<dim3(2, MALL / 64), 256, 0, stream>>>(
            xcur, w1t + (size_t)l * FFH * EMB, ff_b1 + l * FFH, t1bf, MALL, FFH, 128, EMB);
        // FF2 + residual(x) + LN1 -> hbf   (direct, K=128 padded)
        gemm_ln_direct<4, 128, 128, false><<<MALL / 64, 256, 0, stream>>>(
            t1bf, w2t + (size_t)l * 320 * 128, ff_b2 + l * EMB, xcur,
            ln1_g + l * EMB, ln1_b + l * EMB, hbf, nullptr, nullptr, nullptr);
        // ATT: h @ att_w + att_b -> cbf
        gemm_mfma<false><<<dim3(2, MALL / 64), 256, 0, stream>>>(
            hbf, awt + (size_t)l * 96 * EMB, att_b + l * 96, cbf, MALL, 96, 96, EMB);
        // attention (q + d merged) -> o32bf
        attn_both<<<BATCH * NH + BATCH * NH * (LD / 128), 512, 0, stream>>>(
            cbf, mask_q, mask_d, o32bf);
        // OUT + residual(h) + LN2 (-> xcbf for l=0; + mix/normalize -> qdn for l=1)
        if (l == 0) {
            gemm_ln_direct<1, 32, 32, false><<<MALL / 64, 256, 0, stream>>>(
                o32bf, owt, out_b, hbf, ln2_g, ln2_b, xcbf, nullptr, nullptr, nullptr);
            xcur = xcbf;
        } else {
            gemm_ln_direct<1, 32, 32, true><<<MALL / 64, 256, 0, stream>>>(
                o32bf, owt + (size_t)320 * 32, out_b + EMB, hbf,
                ln2_g + EMB, ln2_b + EMB, qdn, xbf, mall, mixer);
        }
    }

    // 2. cosine matrix via MFMA -> cosbf (bf16)
    cos_mfma<<<dim3(LD / 64, BATCH), 256, 0, stream>>>(qdn, qdn + (size_t)MQ * EMB, cosbf);

    // 3. kernel pooling (bf16 cos input)
    pool_kernel<<<(BATCH * LQ) / 4, 256, 0, stream>>>(cosbf, mask_q, mask_d, nn_scaler, lp);

    // 4. final projection
    final_kernel<<<BATCH, 64, 0, stream>>>(lp, dense_w, out);
}